// Round 12
// baseline (217.338 us; speedup 1.0000x reference)
//
#include <hip/hip_runtime.h>
#include <math.h>

typedef int i32x4 __attribute__((ext_vector_type(4)));
typedef int i32x16 __attribute__((ext_vector_type(16)));

#define NT_M 128   // T/64
#define NT_D 32    // D/64
#define NT_F 22    // F/64
#define DDIM 2048
#define FDIM 1408

// Fragment-order byte offset of element (r,k) in a 64x64 i8 tile (4096B).
// Layout = [k-block(2)][row-half(2)][k-halfword(2)][row%32(32)][k%16(16)]
// MFMA fragment read = base + kkblk*2048 + rowhalf*1024 + lane*16: zero conflicts.
// A BK=32 K-slice (one kkblk) is a CONTIGUOUS 2048B chunk -> linear staging.
#define OFFN(r, k)                                                                  \
  (((((k) >> 5)) << 11) + ((((r) >> 5)) << 10) + (((((k) >> 4) & 1)) << 9) +        \
   ((((r) & 31)) << 4) + ((k) & 15))

__device__ __forceinline__ void gld_lds16(const void* gp, void* lp) {
  auto* l = reinterpret_cast<unsigned int __attribute__((address_space(3)))*>(
      (unsigned int)(unsigned long long)(lp));
  const auto* g = reinterpret_cast<const unsigned int __attribute__((address_space(1)))*>(
      (unsigned long long)(gp));
  __builtin_amdgcn_global_load_lds(g, l, 16, 0, 0);
}

__device__ __forceinline__ i32x16 zero16() {
  i32x16 z;
#pragma unroll
  for (int e = 0; e < 16; ++e) z[e] = 0;
  return z;
}

// ---------------- pack x into 3 signed base-256 digit planes, fragment-order tiles ----------------
__global__ __launch_bounds__(256) void pack_x_kernel(const int* __restrict__ x,
                                                     signed char* __restrict__ XD) {
  const int tk = blockIdx.x;   // 0..31   (D tiles)
  const int tm = blockIdx.y;   // 0..127  (T tiles)
  const int tid = threadIdx.x;
  signed char* tile = XD + (size_t)(tm * NT_D + tk) * 3 * 4096;
  const int* base = x + (size_t)tm * 64 * DDIM + tk * 64;
#pragma unroll
  for (int i = 0; i < 4; ++i) {
    const int gi = i * 256 + tid;      // 1024 groups of 4 elements
    const int row = gi >> 4;           // 64 rows
    const int k4 = (gi & 15) << 2;     // k offset, multiple of 4
    const i32x4 v = *(const i32x4*)(base + (size_t)row * DDIM + k4);
    unsigned p0 = 0, p1 = 0, p2 = 0;
#pragma unroll
    for (int j = 0; j < 4; ++j) {
      const int val = v[j];
      const int b0 = (int)(signed char)(val & 0xff);
      const int c = (val - b0) >> 8;
      const int b1 = (int)(signed char)(c & 0xff);
      const int b2 = (c - b1) >> 8;
      p0 |= ((unsigned)(val & 0xff)) << (8 * j);
      p1 |= ((unsigned)(c & 0xff)) << (8 * j);
      p2 |= ((unsigned)(b2 & 0xff)) << (8 * j);
    }
    const int off = OFFN(row, k4);
    *(unsigned*)(tile + off) = p0;
    *(unsigned*)(tile + 4096 + off) = p1;
    *(unsigned*)(tile + 8192 + off) = p2;
  }
}

// ---------------- pack w1/w3/w2 (int32 holding i8 values) into fragment-order tiles ----------------
__global__ __launch_bounds__(256) void pack_w_kernel(const int* __restrict__ w1,
                                                     const int* __restrict__ w3,
                                                     const int* __restrict__ w2,
                                                     signed char* __restrict__ W1T,
                                                     signed char* __restrict__ W3T,
                                                     signed char* __restrict__ W2T) {
  const int which = blockIdx.y;   // 0=w1, 1=w3, 2=w2
  const int t = blockIdx.x;       // 704 tiles each
  const int tid = threadIdx.x;
  const int* src;
  signed char* dst;
  int rowstride, nk;
  if (which == 0)      { src = w1; dst = W1T; rowstride = DDIM; nk = NT_D; }
  else if (which == 1) { src = w3; dst = W3T; rowstride = DDIM; nk = NT_D; }
  else                 { src = w2; dst = W2T; rowstride = FDIM; nk = NT_F; }
  const int tr = t / nk, tk = t % nk;
  signed char* tile = dst + (size_t)t * 4096;
  const int* base = src + (size_t)tr * 64 * rowstride + tk * 64;
#pragma unroll
  for (int i = 0; i < 4; ++i) {
    const int gi = i * 256 + tid;
    const int row = gi >> 4;
    const int k4 = (gi & 15) << 2;
    const i32x4 v = *(const i32x4*)(base + (size_t)row * rowstride + k4);
    const unsigned p = ((unsigned)(v[0] & 0xff)) | ((unsigned)(v[1] & 0xff) << 8) |
                       ((unsigned)(v[2] & 0xff) << 16) | ((unsigned)(v[3] & 0xff) << 24);
    *(unsigned*)(tile + OFFN(row, k4)) = p;
  }
}

// ---------------- gemm1: 64x64 tile, BK=32, 2-buf 20KB LDS (high occupancy) ----------------
// r1=(x@w1^T)>>s1, r2=(x@w3^T)>>s3, gate=(silu_q23(r1)*r2)>>23  (exact int64 semantics)
__global__ __launch_bounds__(256, 4) void gemm1_kernel(
    const signed char* __restrict__ XD, const signed char* __restrict__ W1T,
    const signed char* __restrict__ W3T, signed char* __restrict__ GATE,
    const int* __restrict__ scale1p, const int* __restrict__ scale3p) {
  __shared__ __align__(16) signed char lds[20480];  // 2 bufs x 10240 (A 6KB + B 4KB)
  const int tid = threadIdx.x;
  const int wv = tid >> 6;
  const int lane = tid & 63;
  const int r32 = lane & 31;
  const int g = lane >> 5;
  // XCD-grouping swizzle: all 22 tf-blocks of one tm land on the same XCD.
  const int bi = blockIdx.x;
  const int c = bi & 7;
  const int q = bi >> 3;            // 0..351
  const int tm = (q / 22) * 8 + c;  // 0..127
  const int tf = q % 22;            // 0..21
  const int wm = wv >> 1, wn = wv & 1;

  i32x16 acc10 = zero16(), acc11 = zero16(), acc12 = zero16();
  i32x16 acc30 = zero16(), acc31 = zero16(), acc32 = zero16();

  const signed char* srcAbase = XD + (size_t)tm * NT_D * 3 * 4096;
  const signed char* srcB1base = W1T + (size_t)tf * NT_D * 4096;
  const signed char* srcB3base = W3T + (size_t)tf * NT_D * 4096;

  // Stage one BK=32 slice (10KB): A planes (3x2KB) + w1 (2KB) + w3 (2KB).
  // 640 x 16B chunks over 256 threads: all branches are wave-uniform, and each
  // wave's LDS dests follow base + lane*16 (global_load_lds DMA rule).
  auto stage = [&](int h, int b) {
    signed char* buf = lds + b * 10240;
    const int kt = h >> 1;
    const int kb = (h & 1) << 11;  // kblk byte offset (0 or 2048)
#pragma unroll
    for (int i = 0; i < 3; ++i) {
      const int idx = i * 256 + tid;
      if (idx < 384) {         // A: plane p = idx>>7, 128 chunks each
        const int p = idx >> 7;
        const int off = (idx & 127) << 4;
        gld_lds16(srcAbase + (size_t)kt * 12288 + p * 4096 + kb + off,
                  buf + p * 2048 + off);
      } else if (idx < 512) {  // w1 slice
        const int off = (idx - 384) << 4;
        gld_lds16(srcB1base + (size_t)kt * 4096 + kb + off, buf + 6144 + off);
      } else if (idx < 640) {  // w3 slice
        const int off = (idx - 512) << 4;
        gld_lds16(srcB3base + (size_t)kt * 4096 + kb + off, buf + 8192 + off);
      }
    }
  };

  stage(0, 0);

  const int aoff = (wm << 10) + lane * 16;  // rowhalf = wm within each 2KB plane slice
  const int boff = (wn << 10) + lane * 16;  // rowhalf = wn within each 2KB w slice

  for (int h = 0; h < 2 * NT_D; ++h) {
    const int b = h & 1;
    __syncthreads();  // drains vmcnt(0): buffer b ready
    if (h + 1 < 2 * NT_D) stage(h + 1, b ^ 1);
    const signed char* A = lds + b * 10240;
    const signed char* B = A + 6144;
    const i32x4 a0 = *(const i32x4*)(A + aoff);
    const i32x4 a1 = *(const i32x4*)(A + 2048 + aoff);
    const i32x4 a2 = *(const i32x4*)(A + 4096 + aoff);
    const i32x4 bb1 = *(const i32x4*)(B + boff);
    const i32x4 bb3 = *(const i32x4*)(B + 2048 + boff);
    acc10 = __builtin_amdgcn_mfma_i32_32x32x32_i8(a0, bb1, acc10, 0, 0, 0);
    acc11 = __builtin_amdgcn_mfma_i32_32x32x32_i8(a1, bb1, acc11, 0, 0, 0);
    acc12 = __builtin_amdgcn_mfma_i32_32x32x32_i8(a2, bb1, acc12, 0, 0, 0);
    acc30 = __builtin_amdgcn_mfma_i32_32x32x32_i8(a0, bb3, acc30, 0, 0, 0);
    acc31 = __builtin_amdgcn_mfma_i32_32x32x32_i8(a1, bb3, acc31, 0, 0, 0);
    acc32 = __builtin_amdgcn_mfma_i32_32x32x32_i8(a2, bb3, acc32, 0, 0, 0);
  }

  const int s1v = scale1p[0];
  const int s3v = scale3p[0];
  signed char* gt = GATE + (size_t)(tm * NT_F + tf) * 4096;
  const double QINV = 1.0 / 8388608.0;
  // OFFN(ml, colf) with ml = wm*32+rowe, colf = wn*32+r32:
  const int ebase = (wn << 11) + (wm << 10) + ((r32 >> 4) << 9) + (r32 & 15);
#pragma unroll
  for (int e = 0; e < 16; ++e) {
    const int rowe = (e & 3) + 8 * (e >> 2) + 4 * g;
    const long long av1 =
        (long long)acc10[e] + ((long long)acc11[e] << 8) + ((long long)acc12[e] << 16);
    const long long r1 = av1 >> s1v;
    const long long av3 =
        (long long)acc30[e] + ((long long)acc31[e] << 8) + ((long long)acc32[e] << 16);
    const long long r2 = av3 >> s3v;
    // Exact silu: |r1| <= 2^14 so |xf| <= 2^-9; sigma = 0.5 + xf/4 - xf^3/48,
    // truncation < 6e-17 (< 1 ulp of 0.5).
    const double xf = (double)r1 * QINV;
    const double x2 = xf * xf;
    const double sg = 0.5 + xf * (0.25 - x2 * (1.0 / 48.0));
    const long long s1q = (long long)rint((double)r1 * sg);
    const long long gv = (s1q * r2) >> 23;
    gt[ebase + rowe * 16] = (signed char)gv;
  }
}

// ---------------- gemm2: q = (gate @ w2^T) >> s2, int32 out; BK=32, 2-buf 16KB ----------------
__global__ __launch_bounds__(256, 4) void gemm2_kernel(
    const signed char* __restrict__ GATE, const signed char* __restrict__ W2T,
    int* __restrict__ out, const int* __restrict__ scale2p) {
  __shared__ __align__(16) signed char lds[16384];  // 2 bufs x 8192 (A 4KB + B 4KB)
  const int tid = threadIdx.x;
  const int wv = tid >> 6;
  const int lane = tid & 63;
  const int r32 = lane & 31;
  const int g = lane >> 5;
  // XCD-grouping swizzle: 1024 blocks = 8 XCDs * 8 tm * 16 tn
  const int bi = blockIdx.x;
  const int c = bi & 7;
  const int q = bi >> 3;           // 0..127
  const int tm = (q >> 4) * 8 + c; // 0..63 (T/128)
  const int tn = q & 15;           // 0..15 (D/128)
  const int wm = wv >> 1, wn = wv & 1;

  i32x16 acc00 = zero16(), acc01 = zero16(), acc10 = zero16(), acc11 = zero16();

  // Stage one BK=32 slice (8KB): 2 gate m-tiles (2x2KB) + 2 w2 d-tiles (2x2KB).
  auto stage = [&](int h, int b) {
    signed char* buf = lds + b * 8192;
    const int kt = h >> 1;
    const int kb = (h & 1) << 11;
#pragma unroll
    for (int i = 0; i < 2; ++i) {
      const int idx = i * 256 + tid;
      if (idx < 256) {  // A: tile = idx>>7, 128 chunks each
        const int t0 = idx >> 7;
        const int off = (idx & 127) << 4;
        gld_lds16(GATE + ((size_t)((tm * 2 + t0) * NT_F + kt)) * 4096 + kb + off,
                  buf + t0 * 2048 + off);
      } else {          // B: tile = (idx-256)>>7
        const int t0 = (idx - 256) >> 7;
        const int off = (idx & 127) << 4;
        gld_lds16(W2T + ((size_t)((tn * 2 + t0) * NT_F + kt)) * 4096 + kb + off,
                  buf + 4096 + t0 * 2048 + off);
      }
    }
  };

  stage(0, 0);
  const int loff = lane * 16;

  for (int h = 0; h < 2 * NT_F; ++h) {
    const int b = h & 1;
    __syncthreads();
    if (h + 1 < 2 * NT_F) stage(h + 1, b ^ 1);
    const signed char* A = lds + b * 8192 + wm * 2048;
    const signed char* B = lds + b * 8192 + 4096 + wn * 2048;
    const i32x4 a0 = *(const i32x4*)(A + loff);          // rows 0-31 of wave m-tile
    const i32x4 a1 = *(const i32x4*)(A + 1024 + loff);   // rows 32-63
    const i32x4 b0 = *(const i32x4*)(B + loff);
    const i32x4 b1 = *(const i32x4*)(B + 1024 + loff);
    acc00 = __builtin_amdgcn_mfma_i32_32x32x32_i8(a0, b0, acc00, 0, 0, 0);
    acc01 = __builtin_amdgcn_mfma_i32_32x32x32_i8(a0, b1, acc01, 0, 0, 0);
    acc10 = __builtin_amdgcn_mfma_i32_32x32x32_i8(a1, b0, acc10, 0, 0, 0);
    acc11 = __builtin_amdgcn_mfma_i32_32x32x32_i8(a1, b1, acc11, 0, 0, 0);
  }

  const int s2v = scale2p[0];
  int* obase = out + (size_t)(tm * 128 + wm * 64) * DDIM + tn * 128 + wn * 64;
#pragma unroll
  for (int e = 0; e < 16; ++e) {
    const int rowe = (e & 3) + 8 * (e >> 2) + 4 * g;
    obase[(size_t)rowe * DDIM + r32] = acc00[e] >> s2v;
    obase[(size_t)rowe * DDIM + 32 + r32] = acc01[e] >> s2v;
    obase[(size_t)(rowe + 32) * DDIM + r32] = acc10[e] >> s2v;
    obase[(size_t)(rowe + 32) * DDIM + 32 + r32] = acc11[e] >> s2v;
  }
}

extern "C" void kernel_launch(void* const* d_in, const int* in_sizes, int n_in,
                              void* d_out, int out_size, void* d_ws, size_t ws_size,
                              hipStream_t stream) {
  if (n_in < 7) return;
  const int* x = (const int*)d_in[0];
  const int* w1 = (const int*)d_in[1];
  const int* w2 = (const int*)d_in[2];
  const int* w3 = (const int*)d_in[3];
  const int* s1 = (const int*)d_in[4];
  const int* s2 = (const int*)d_in[5];
  const int* s3 = (const int*)d_in[6];
  signed char* ws = (signed char*)d_ws;
  int* out = (int*)d_out;

  const size_t XD_OFF = 0;
  const size_t XD_SZ = (size_t)NT_M * NT_D * 3 * 4096;   // 50331648
  const size_t WT_SZ = (size_t)NT_F * NT_D * 4096;       // 2883584
  const size_t W1_OFF = XD_OFF + XD_SZ;
  const size_t W3_OFF = W1_OFF + WT_SZ;
  const size_t W2_OFF = W3_OFF + WT_SZ;
  const size_t GATE_OFF = W2_OFF + WT_SZ;
  const size_t GATE_SZ = (size_t)NT_M * NT_F * 4096;     // 11534336
  if (ws_size < GATE_OFF + GATE_SZ) return;  // ~70.5 MB required

  pack_x_kernel<<<dim3(NT_D, NT_M), 256, 0, stream>>>(x, ws + XD_OFF);
  pack_w_kernel<<<dim3(704, 3), 256, 0, stream>>>(w1, w3, w2, ws + W1_OFF, ws + W3_OFF,
                                                  ws + W2_OFF);
  gemm1_kernel<<<dim3(2816), 256, 0, stream>>>(ws + XD_OFF, ws + W1_OFF, ws + W3_OFF,
                                               ws + GATE_OFF, s1, s3);
  gemm2_kernel<<<dim3(1024), 256, 0, stream>>>(ws + GATE_OFF, ws + W2_OFF, out, s2);
}

// Round 13
// 193.291 us; speedup vs baseline: 1.1244x; 1.1244x over previous
//
#include <hip/hip_runtime.h>
#include <math.h>

typedef int i32x4 __attribute__((ext_vector_type(4)));
typedef int i32x16 __attribute__((ext_vector_type(16)));

#define NT_M 128   // T/64
#define NT_D 32    // D/64
#define NT_F 22    // F/64
#define DDIM 2048
#define FDIM 1408

// Fragment-order byte offset of element (r,k) in a 64x64 i8 tile (4096B).
// Layout = [k-block(2)][row-half(2)][k-halfword(2)][row%32(32)][k%16(16)]
// MFMA fragment read = base + kkblk*2048 + rowhalf*1024 + lane*16: zero conflicts.
#define OFFN(r, k)                                                                  \
  (((((k) >> 5)) << 11) + ((((r) >> 5)) << 10) + (((((k) >> 4) & 1)) << 9) +        \
   ((((r) & 31)) << 4) + ((k) & 15))

__device__ __forceinline__ void gld_lds16(const void* gp, void* lp) {
  auto* l = reinterpret_cast<unsigned int __attribute__((address_space(3)))*>(
      (unsigned int)(unsigned long long)(lp));
  const auto* g = reinterpret_cast<const unsigned int __attribute__((address_space(1)))*>(
      (unsigned long long)(gp));
  __builtin_amdgcn_global_load_lds(g, l, 16, 0, 0);
}

__device__ __forceinline__ i32x16 zero16() {
  i32x16 z;
#pragma unroll
  for (int e = 0; e < 16; ++e) z[e] = 0;
  return z;
}

// ---------------- pack x into 3 signed base-256 digit planes, fragment-order tiles ----------------
__global__ __launch_bounds__(256) void pack_x_kernel(const int* __restrict__ x,
                                                     signed char* __restrict__ XD) {
  const int tk = blockIdx.x;   // 0..31   (D tiles)
  const int tm = blockIdx.y;   // 0..127  (T tiles)
  const int tid = threadIdx.x;
  signed char* tile = XD + (size_t)(tm * NT_D + tk) * 3 * 4096;
  const int* base = x + (size_t)tm * 64 * DDIM + tk * 64;
#pragma unroll
  for (int i = 0; i < 4; ++i) {
    const int gi = i * 256 + tid;      // 1024 groups of 4 elements
    const int row = gi >> 4;           // 64 rows
    const int k4 = (gi & 15) << 2;     // k offset, multiple of 4
    const i32x4 v = *(const i32x4*)(base + (size_t)row * DDIM + k4);
    unsigned p0 = 0, p1 = 0, p2 = 0;
#pragma unroll
    for (int j = 0; j < 4; ++j) {
      const int val = v[j];
      const int b0 = (int)(signed char)(val & 0xff);
      const int c = (val - b0) >> 8;
      const int b1 = (int)(signed char)(c & 0xff);
      const int b2 = (c - b1) >> 8;
      p0 |= ((unsigned)(val & 0xff)) << (8 * j);
      p1 |= ((unsigned)(c & 0xff)) << (8 * j);
      p2 |= ((unsigned)(b2 & 0xff)) << (8 * j);
    }
    const int off = OFFN(row, k4);
    *(unsigned*)(tile + off) = p0;
    *(unsigned*)(tile + 4096 + off) = p1;
    *(unsigned*)(tile + 8192 + off) = p2;
  }
}

// ---------------- pack w1/w3/w2 (int32 holding i8 values) into fragment-order tiles ----------------
__global__ __launch_bounds__(256) void pack_w_kernel(const int* __restrict__ w1,
                                                     const int* __restrict__ w3,
                                                     const int* __restrict__ w2,
                                                     signed char* __restrict__ W1T,
                                                     signed char* __restrict__ W3T,
                                                     signed char* __restrict__ W2T) {
  const int which = blockIdx.y;   // 0=w1, 1=w3, 2=w2
  const int t = blockIdx.x;       // 704 tiles each
  const int tid = threadIdx.x;
  const int* src;
  signed char* dst;
  int rowstride, nk;
  if (which == 0)      { src = w1; dst = W1T; rowstride = DDIM; nk = NT_D; }
  else if (which == 1) { src = w3; dst = W3T; rowstride = DDIM; nk = NT_D; }
  else                 { src = w2; dst = W2T; rowstride = FDIM; nk = NT_F; }
  const int tr = t / nk, tk = t % nk;
  signed char* tile = dst + (size_t)t * 4096;
  const int* base = src + (size_t)tr * 64 * rowstride + tk * 64;
#pragma unroll
  for (int i = 0; i < 4; ++i) {
    const int gi = i * 256 + tid;
    const int row = gi >> 4;
    const int k4 = (gi & 15) << 2;
    const i32x4 v = *(const i32x4*)(base + (size_t)row * rowstride + k4);
    const unsigned p = ((unsigned)(v[0] & 0xff)) | ((unsigned)(v[1] & 0xff) << 8) |
                       ((unsigned)(v[2] & 0xff) << 16) | ((unsigned)(v[3] & 0xff) << 24);
    *(unsigned*)(tile + OFFN(row, k4)) = p;
  }
}

// ---------------- gemm1: 64x64 tile, 4 waves, 2-buf LDS, conflict-free; 3 waves/EU ----------------
// In-loop regs: 96 AGPR acc + VGPRs. (256,3) directs the allocator to fit <=170
// total -> 3 waves/SIMD instead of 2 (+50% TLP). Spill canary: WRITE_SIZE.
// r1=(x@w1^T)>>s1, r2=(x@w3^T)>>s3, gate=(silu_q23(r1)*r2)>>23  (exact int64 semantics)
__global__ __launch_bounds__(256, 3) void gemm1_kernel(
    const signed char* __restrict__ XD, const signed char* __restrict__ W1T,
    const signed char* __restrict__ W3T, signed char* __restrict__ GATE,
    const int* __restrict__ scale1p, const int* __restrict__ scale3p) {
  __shared__ __align__(16) signed char lds[40960];  // 2 bufs x (A 12288 + B 8192)
  const int tid = threadIdx.x;
  const int wv = tid >> 6;
  const int lane = tid & 63;
  const int r32 = lane & 31;
  const int g = lane >> 5;
  // XCD-grouping swizzle: all 22 tf-blocks of one tm land on the same XCD.
  const int bi = blockIdx.x;
  const int c = bi & 7;
  const int q = bi >> 3;            // 0..351
  const int tm = (q / 22) * 8 + c;  // 0..127
  const int tf = q % 22;            // 0..21
  const int wm = wv >> 1, wn = wv & 1;

  i32x16 acc10 = zero16(), acc11 = zero16(), acc12 = zero16();
  i32x16 acc30 = zero16(), acc31 = zero16(), acc32 = zero16();

  const signed char* srcAbase = XD + (size_t)tm * NT_D * 3 * 4096;
  const signed char* srcB1base = W1T + (size_t)tf * NT_D * 4096;
  const signed char* srcB3base = W3T + (size_t)tf * NT_D * 4096;

  auto stage = [&](int kt, int b) {
    signed char* buf = lds + b * 20480;
#pragma unroll
    for (int j = 0; j < 3; ++j) {
      const int ch = wv * 3 + j;  // 12 chunks of 1KB = 3 digit planes
      gld_lds16(srcAbase + (size_t)kt * 12288 + ch * 1024 + lane * 16, buf + ch * 1024);
    }
#pragma unroll
    for (int j = 0; j < 2; ++j) {
      const int ch = wv * 2 + j;  // 8 chunks: 0-3 = w1 tile, 4-7 = w3 tile
      const signed char* s = (ch < 4) ? srcB1base + (size_t)kt * 4096 + ch * 1024
                                      : srcB3base + (size_t)kt * 4096 + (ch - 4) * 1024;
      gld_lds16(s + lane * 16, buf + 12288 + ch * 1024);
    }
  };

  // Canonical fragment addresses: base + kk*2048 + half*1024 + lane*16 (stride-16/lane).
  const int aoff = (wm << 10) + lane * 16;
  const int boff = (wn << 10) + lane * 16;

  auto compute = [&](int b) {
    const signed char* A = lds + b * 20480;
    const signed char* B = lds + b * 20480 + 12288;
#pragma unroll
    for (int kk = 0; kk < 2; ++kk) {
      const int ko = kk * 2048;
      const i32x4 a0 = *(const i32x4*)(A + ko + aoff);
      const i32x4 a1 = *(const i32x4*)(A + 4096 + ko + aoff);
      const i32x4 a2 = *(const i32x4*)(A + 8192 + ko + aoff);
      const i32x4 bb1 = *(const i32x4*)(B + ko + boff);
      const i32x4 bb3 = *(const i32x4*)(B + 4096 + ko + boff);
      acc10 = __builtin_amdgcn_mfma_i32_32x32x32_i8(a0, bb1, acc10, 0, 0, 0);
      acc11 = __builtin_amdgcn_mfma_i32_32x32x32_i8(a1, bb1, acc11, 0, 0, 0);
      acc12 = __builtin_amdgcn_mfma_i32_32x32x32_i8(a2, bb1, acc12, 0, 0, 0);
      acc30 = __builtin_amdgcn_mfma_i32_32x32x32_i8(a0, bb3, acc30, 0, 0, 0);
      acc31 = __builtin_amdgcn_mfma_i32_32x32x32_i8(a1, bb3, acc31, 0, 0, 0);
      acc32 = __builtin_amdgcn_mfma_i32_32x32x32_i8(a2, bb3, acc32, 0, 0, 0);
    }
  };

  stage(0, 0);

  for (int kt = 0; kt < NT_D; ++kt) {
    const int b = kt & 1;
    __syncthreads();  // drains vmcnt(0): buffer b ready
    if (kt + 1 < NT_D) stage(kt + 1, b ^ 1);
    compute(b);
  }

  const int s1v = scale1p[0];
  const int s3v = scale3p[0];
  signed char* gt = GATE + (size_t)(tm * NT_F + tf) * 4096;
  const double QINV = 1.0 / 8388608.0;
  // OFFN(ml, colf) with ml = wm*32+rowe, colf = wn*32+r32:
  const int ebase = (wn << 11) + (wm << 10) + ((r32 >> 4) << 9) + (r32 & 15);
#pragma unroll
  for (int e = 0; e < 16; ++e) {
    const int rowe = (e & 3) + 8 * (e >> 2) + 4 * g;
    const long long av1 =
        (long long)acc10[e] + ((long long)acc11[e] << 8) + ((long long)acc12[e] << 16);
    const long long r1 = av1 >> s1v;
    const long long av3 =
        (long long)acc30[e] + ((long long)acc31[e] << 8) + ((long long)acc32[e] << 16);
    const long long r2 = av3 >> s3v;
    // Exact silu: |r1| <= 2^14 so |xf| <= 2^-9; sigma = 0.5 + xf/4 - xf^3/48,
    // truncation < 6e-17 (< 1 ulp of 0.5) -- exceeds the accuracy of the libm
    // exp path already verified bit-exact (rint margin ~4e-8).
    const double xf = (double)r1 * QINV;
    const double x2 = xf * xf;
    const double sg = 0.5 + xf * (0.25 - x2 * (1.0 / 48.0));
    const long long s1q = (long long)rint((double)r1 * sg);
    const long long gv = (s1q * r2) >> 23;
    gt[ebase + rowe * 16] = (signed char)gv;
  }
}

// ---------------- gemm2: q = (gate @ w2^T) >> s2, int32 out; 2-buf, conflict-free reads ----------------
__global__ __launch_bounds__(256, 2) void gemm2_kernel(
    const signed char* __restrict__ GATE, const signed char* __restrict__ W2T,
    int* __restrict__ out, const int* __restrict__ scale2p) {
  __shared__ __align__(16) signed char lds[32768];  // 2 bufs x (A 8192 + B 8192)
  const int tid = threadIdx.x;
  const int wv = tid >> 6;
  const int lane = tid & 63;
  const int r32 = lane & 31;
  const int g = lane >> 5;
  // XCD-grouping swizzle: 1024 blocks = 8 XCDs * 8 tm * 16 tn
  const int bi = blockIdx.x;
  const int c = bi & 7;
  const int q = bi >> 3;           // 0..127
  const int tm = (q >> 4) * 8 + c; // 0..63 (T/128)
  const int tn = q & 15;           // 0..15 (D/128)
  const int wm = wv >> 1, wn = wv & 1;

  i32x16 acc00 = zero16(), acc01 = zero16(), acc10 = zero16(), acc11 = zero16();

  auto stage = [&](int kt, int b) {
    signed char* buf = lds + b * 16384;
#pragma unroll
    for (int j = 0; j < 2; ++j) {
      const int ch = wv * 2 + j;  // 8 chunks: 2 gate m-tiles
      gld_lds16(GATE + ((size_t)((tm * 2 + (ch >> 2)) * NT_F + kt)) * 4096 + (ch & 3) * 1024 +
                    lane * 16,
                buf + ch * 1024);
    }
#pragma unroll
    for (int j = 0; j < 2; ++j) {
      const int ch = wv * 2 + j;  // 8 chunks: 2 w2 d-tiles
      gld_lds16(W2T + ((size_t)((tn * 2 + (ch >> 2)) * NT_F + kt)) * 4096 + (ch & 3) * 1024 +
                    lane * 16,
                buf + 8192 + ch * 1024);
    }
  };

  const int loff = lane * 16;

  auto compute = [&](int b) {
    const signed char* A = lds + b * 16384 + wm * 4096;
    const signed char* B = lds + b * 16384 + 8192 + wn * 4096;
#pragma unroll
    for (int kk = 0; kk < 2; ++kk) {
      const int ko = kk * 2048;
      const i32x4 a0 = *(const i32x4*)(A + ko + loff);          // rows 0-31 of wave tile
      const i32x4 a1 = *(const i32x4*)(A + ko + 1024 + loff);   // rows 32-63
      const i32x4 b0 = *(const i32x4*)(B + ko + loff);
      const i32x4 b1 = *(const i32x4*)(B + ko + 1024 + loff);
      acc00 = __builtin_amdgcn_mfma_i32_32x32x32_i8(a0, b0, acc00, 0, 0, 0);
      acc01 = __builtin_amdgcn_mfma_i32_32x32x32_i8(a0, b1, acc01, 0, 0, 0);
      acc10 = __builtin_amdgcn_mfma_i32_32x32x32_i8(a1, b0, acc10, 0, 0, 0);
      acc11 = __builtin_amdgcn_mfma_i32_32x32x32_i8(a1, b1, acc11, 0, 0, 0);
    }
  };

  stage(0, 0);

  for (int kt = 0; kt < NT_F; ++kt) {
    const int b = kt & 1;
    __syncthreads();
    if (kt + 1 < NT_F) stage(kt + 1, b ^ 1);
    compute(b);
  }

  const int s2v = scale2p[0];
  int* obase = out + (size_t)(tm * 128 + wm * 64) * DDIM + tn * 128 + wn * 64;
#pragma unroll
  for (int e = 0; e < 16; ++e) {
    const int rowe = (e & 3) + 8 * (e >> 2) + 4 * g;
    obase[(size_t)rowe * DDIM + r32] = acc00[e] >> s2v;
    obase[(size_t)rowe * DDIM + 32 + r32] = acc01[e] >> s2v;
    obase[(size_t)(rowe + 32) * DDIM + r32] = acc10[e] >> s2v;
    obase[(size_t)(rowe + 32) * DDIM + 32 + r32] = acc11[e] >> s2v;
  }
}

extern "C" void kernel_launch(void* const* d_in, const int* in_sizes, int n_in,
                              void* d_out, int out_size, void* d_ws, size_t ws_size,
                              hipStream_t stream) {
  if (n_in < 7) return;
  const int* x = (const int*)d_in[0];
  const int* w1 = (const int*)d_in[1];
  const int* w2 = (const int*)d_in[2];
  const int* w3 = (const int*)d_in[3];
  const int* s1 = (const int*)d_in[4];
  const int* s2 = (const int*)d_in[5];
  const int* s3 = (const int*)d_in[6];
  signed char* ws = (signed char*)d_ws;
  int* out = (int*)d_out;

  const size_t XD_OFF = 0;
  const size_t XD_SZ = (size_t)NT_M * NT_D * 3 * 4096;   // 50331648
  const size_t WT_SZ = (size_t)NT_F * NT_D * 4096;       // 2883584
  const size_t W1_OFF = XD_OFF + XD_SZ;
  const size_t W3_OFF = W1_OFF + WT_SZ;
  const size_t W2_OFF = W3_OFF + WT_SZ;
  const size_t GATE_OFF = W2_OFF + WT_SZ;
  const size_t GATE_SZ = (size_t)NT_M * NT_F * 4096;     // 11534336
  if (ws_size < GATE_OFF + GATE_SZ) return;  // ~70.5 MB required

  pack_x_kernel<<<dim3(NT_D, NT_M), 256, 0, stream>>>(x, ws + XD_OFF);
  pack_w_kernel<<<dim3(704, 3), 256, 0, stream>>>(w1, w3, w2, ws + W1_OFF, ws + W3_OFF,
                                                  ws + W2_OFF);
  gemm1_kernel<<<dim3(2816), 256, 0, stream>>>(ws + XD_OFF, ws + W1_OFF, ws + W3_OFF,
                                               ws + GATE_OFF, s1, s3);
  gemm2_kernel<<<dim3(1024), 256, 0, stream>>>(ws + GATE_OFF, ws + W2_OFF, out, s2);
}